// Round 5
// baseline (1284.962 us; speedup 1.0000x reference)
//
#include <hip/hip_runtime.h>
#include <hip/hip_fp16.h>
#include <math.h>

// SO3 DiT layer, MI355X fp32. N=6000, E=72000, P=2, L=2, M=9, F=64, H=4, DH=16
// R3: coalesced LDS staging for edge/proj GEMMs (broadcast loads were the
// bottleneck, scalar OR vector flavored). 1370 -> 1080 us.
// R4: fused MLP (h never in memory) but single 375-block grid with serial
// 18-pm loop -> 8.7% occupancy, 545 us. Fusion right, parallelism wrong.
// R5: split the one cross-pm dependency (gelu gate from pm=0) into k_gate
// (6.1 MB gate buffer), then k_mlp_par runs a fully parallel (n-tile, pm)
// grid (6750 blocks), 36 KB LDS, no serial pm loop.

#define NN 6000
#define EE 72000

__device__ __forceinline__ float wsum(float v) {
#pragma unroll
  for (int o = 32; o >= 1; o >>= 1) v += __shfl_xor(v, o, 64);
  return v;
}
__device__ __forceinline__ int deg_of(int m) { return (m == 0) ? 0 : ((m < 4) ? 1 : 2); }
// order-preserving float->uint for atomicMax-based segment max
__device__ __forceinline__ unsigned fenc(float x) {
  unsigned u = __float_as_uint(x);
  return (u & 0x80000000u) ? ~u : (u | 0x80000000u);
}
__device__ __forceinline__ float fdec(unsigned k) {
  unsigned u = (k & 0x80000000u) ? (k & 0x7fffffffu) : ~k;
  return __uint_as_float(u);
}

// ---------------- K1a: LayerNorm(T=64) + SiLU, one wave per node ----------------
__global__ __launch_bounds__(256) void k_ln_t(const float* __restrict__ ft,
                                              const float* __restrict__ lns,
                                              const float* __restrict__ lnb,
                                              float* __restrict__ sbuf) {
  int w = (blockIdx.x * 256 + threadIdx.x) >> 6;  // node, exact 6000
  int lane = threadIdx.x & 63;
  float t = ft[(size_t)w * 64 + lane];
  float mu = wsum(t) * (1.f / 64.f);
  float d = t - mu;
  float var = wsum(d * d) * (1.f / 64.f);
  float cin = d * rsqrtf(var + 1e-6f) * lns[lane] + lnb[lane];
  sbuf[(size_t)w * 64 + lane] = cin / (1.f + expf(-cin));
}

// ---------------- K1b: c = silu @ W_c + b_c  (64 -> 1664), 8 nodes/block ----------------
__global__ __launch_bounds__(256) void k_cond_mm(const float* __restrict__ sbuf,
                                                 const float* __restrict__ Wc,
                                                 const float* __restrict__ bc,
                                                 float* __restrict__ c) {
  __shared__ __align__(16) float st[8 * 64];  // 2 KB
  int n0 = blockIdx.x * 8;  // 750 blocks
  for (int i = threadIdx.x; i < 512; i += 256) st[i] = sbuf[(size_t)n0 * 64 + i];
  __syncthreads();
  for (int jj = threadIdx.x; jj < 1664; jj += 256) {
    float acc[8] = {0, 0, 0, 0, 0, 0, 0, 0};
#pragma unroll 8
    for (int k2 = 0; k2 < 64; k2++) {
      float wv = Wc[(size_t)k2 * 1664 + jj];
#pragma unroll
      for (int nd = 0; nd < 8; nd++) acc[nd] += st[nd * 64 + k2] * wv;
    }
    float b = bc[jj];
#pragma unroll
    for (int nd = 0; nd < 8; nd++) c[(size_t)(n0 + nd) * 1664 + jj] = acc[nd] + b;
  }
}

// ---------------- K2/K8: eqv layernorm + modulate, one wave per (n,p) ----------------
__global__ __launch_bounds__(256) void k_lnmod(const float* __restrict__ xin,
                                               const float* __restrict__ c,
                                               float* __restrict__ xout,
                                               int goff, int boff) {
  int w = (blockIdx.x * 256 + threadIdx.x) >> 6;  // (n,p) pair, exact 12000
  int lane = threadIdx.x & 63;
  int n = w >> 1, p = w & 1;
  const float* xb = xin + (size_t)w * 576 + lane;
  float x0 = xb[0], x1 = xb[64], x2 = xb[128], x3 = xb[192], x4 = xb[256];
  float x5 = xb[320], x6 = xb[384], x7 = xb[448], x8 = xb[512];
  float mu = wsum(x0) * (1.f / 64.f);
  x0 -= mu;
  float n20 = x0 * x0;
  float n21 = (x1 * x1 + x2 * x2 + x3 * x3) * (1.f / 3.f);
  float n22 = (x4 * x4 + x5 * x5 + x6 * x6 + x7 * x7 + x8 * x8) * (1.f / 5.f);
  n20 = wsum(n20) * (1.f / 64.f);
  n21 = wsum(n21) * (1.f / 64.f);
  n22 = wsum(n22) * (1.f / 64.f);
  float i0 = rsqrtf(n20 + 1e-6f), i1 = rsqrtf(n21 + 1e-6f), i2 = rsqrtf(n22 + 1e-6f);
  const float* cb = c + (size_t)n * 1664;
  float g0 = 1.f + cb[goff + p * 192 + lane];
  float g1 = 1.f + cb[goff + p * 192 + 64 + lane];
  float g2 = 1.f + cb[goff + p * 192 + 128 + lane];
  float bsh = cb[boff + lane];
  float* ob = xout + (size_t)w * 576 + lane;
  ob[0] = x0 * i0 * g0 + bsh;
  ob[64] = x1 * i1 * g1;
  ob[128] = x2 * i1 * g1;
  ob[192] = x3 * i1 * g1;
  ob[256] = x4 * i2 * g2;
  ob[320] = x5 * i2 * g2;
  ob[384] = x6 * i2 * g2;
  ob[448] = x7 * i2 * g2;
  ob[512] = x8 * i2 * g2;
}

// ---------------- CSR build: count, scan, fill ----------------
__global__ __launch_bounds__(256) void k_count(const int* __restrict__ dst_idx,
                                               const float* __restrict__ cutoff,
                                               float* __restrict__ cnt,
                                               float* __restrict__ cutsum) {
  int e = blockIdx.x * 256 + threadIdx.x;
  if (e >= EE) return;
  int d = dst_idx[e];
  unsafeAtomicAdd(cnt + d, 1.f);
  unsafeAtomicAdd(cutsum + d, cutoff[e]);
}

__global__ __launch_bounds__(1024) void k_scan(const float* __restrict__ cnt,
                                               int* __restrict__ rowptr,
                                               int* __restrict__ fillc) {
  __shared__ int part[1024];
  int t = threadIdx.x;
  int base = t * 6;  // 1024*6 = 6144 >= 6000
  int lc[6];
  int s = 0;
#pragma unroll
  for (int i = 0; i < 6; i++) {
    int idx = base + i;
    int vv = (idx < NN) ? (int)(cnt[idx] + 0.5f) : 0;
    lc[i] = s;
    s += vv;
  }
  part[t] = s;
  __syncthreads();
  for (int o = 1; o < 1024; o <<= 1) {
    int vv = (t >= o) ? part[t - o] : 0;
    __syncthreads();
    part[t] += vv;
    __syncthreads();
  }
  int ex = (t == 0) ? 0 : part[t - 1];
#pragma unroll
  for (int i = 0; i < 6; i++) {
    int idx = base + i;
    if (idx < NN) {
      int p = ex + lc[i];
      rowptr[idx] = p;
      fillc[idx] = p;
    }
  }
  if (t == 1023) rowptr[NN] = part[1023];  // == EE
}

__global__ __launch_bounds__(256) void k_fill(const int* __restrict__ dst_idx,
                                              const int* __restrict__ src_idx,
                                              const float* __restrict__ cutoff,
                                              int* __restrict__ fillc,
                                              int* __restrict__ eids,
                                              int* __restrict__ dsts,
                                              int* __restrict__ srcs,
                                              float* __restrict__ cuts) {
  int e = blockIdx.x * 256 + threadIdx.x;
  if (e >= EE) return;
  int d = dst_idx[e];
  int pos = atomicAdd(fillc + d, 1);
  eids[pos] = e;
  dsts[pos] = d;
  srcs[pos] = src_idx[e];
  cuts[pos] = cutoff[e];
}

// ---------------- K3: fused q/k/v projection, LDS-tiled, fp16 out ----------------
// grid (375, 18), 192 threads: wave = one of {q,k,v}; 16 nodes/block staged once.
__global__ __launch_bounds__(192) void k_qkv2(const float* __restrict__ xpre,
                                              const float* __restrict__ Wq,
                                              const float* __restrict__ Wk,
                                              const float* __restrict__ Wv,
                                              __half* __restrict__ qh,
                                              __half* __restrict__ kh,
                                              __half* __restrict__ vh) {
  __shared__ __align__(16) float xt[16 * 64];  // 4 KB
  int pm = blockIdx.y;
  int p = pm / 9, dm = deg_of(pm % 9);
  int n0 = blockIdx.x * 16;
  int mat = threadIdx.x >> 6;  // wave-uniform: 0=q 1=k 2=v
  int g = threadIdx.x & 63;
  for (int i = threadIdx.x; i < 1024; i += 192) {
    int r = i >> 6, f = i & 63;
    xt[i] = xpre[((size_t)(n0 + r) * 18 + pm) * 64 + f];
  }
  const float* Wsel = (mat == 0) ? Wq : ((mat == 1) ? Wk : Wv);
  const float* Wb = Wsel + (size_t)(p * 3 + dm) * 4096;
  __half* ob = (mat == 0) ? qh : ((mat == 1) ? kh : vh);
  float wreg[64];
#pragma unroll
  for (int f = 0; f < 64; f++) wreg[f] = Wb[f * 64 + g];
  __syncthreads();
  for (int r = 0; r < 16; r++) {
    float acc = 0.f;
#pragma unroll
    for (int f4 = 0; f4 < 16; f4++) {
      float4 a = *(const float4*)(xt + r * 64 + f4 * 4);  // LDS broadcast
      acc += a.x * wreg[4 * f4] + a.y * wreg[4 * f4 + 1] + a.z * wreg[4 * f4 + 2] +
             a.w * wreg[4 * f4 + 3];
    }
    ob[((size_t)(n0 + r) * 18 + pm) * 64 + g] = __float2half(acc);
  }
}

// ---------------- K4: LDS-tiled eq+ev GEMM + qk logits + segment max ----------------
// grid 4500 blocks x 256: 16 slots/block staged coalesced; wave handles 4 slots.
// eq stays in registers (never materialized); ev written fp16 once.
__global__ __launch_bounds__(256) void k_edge(const float* __restrict__ fe,
                                              const float* __restrict__ Weqk,
                                              const float* __restrict__ Wev,
                                              const __half* __restrict__ qh,
                                              const __half* __restrict__ kh,
                                              const int* __restrict__ eids,
                                              const int* __restrict__ dsts,
                                              const int* __restrict__ srcs,
                                              __half* __restrict__ evh,
                                              float* __restrict__ logw,
                                              unsigned* __restrict__ lmax) {
  __shared__ __align__(16) float ft[16 * 576];  // 36 KB
  int s0 = blockIdx.x * 16;
  int g = threadIdx.x & 63;
  int w = threadIdx.x >> 6;
  float wq[64], wv[64];
#pragma unroll
  for (int f = 0; f < 64; f++) {
    wq[f] = Weqk[f * 64 + g];
    wv[f] = Wev[f * 64 + g];
  }
  {  // coalesced stage: 16 threads per slot, 9 float4 each (256B segments)
    int sl = threadIdx.x >> 4, j = threadIdx.x & 15;
    const float* sp = fe + (size_t)eids[s0 + sl] * 576;
#pragma unroll
    for (int i = 0; i < 9; i++) {
      *(float4*)(ft + sl * 576 + i * 64 + j * 4) = *(const float4*)(sp + i * 64 + j * 4);
    }
  }
  __syncthreads();
  for (int ss = 0; ss < 4; ss++) {
    int sl = w * 4 + ss;
    int s = s0 + sl;
    float eq[9];
#pragma unroll
    for (int m = 0; m < 9; m++) {
      float eqm = 0.f, evm = 0.f;
#pragma unroll
      for (int f4 = 0; f4 < 16; f4++) {
        float4 a = *(const float4*)(ft + sl * 576 + m * 64 + f4 * 4);  // LDS broadcast
        eqm += a.x * wq[4 * f4] + a.y * wq[4 * f4 + 1] + a.z * wq[4 * f4 + 2] +
               a.w * wq[4 * f4 + 3];
        evm += a.x * wv[4 * f4] + a.y * wv[4 * f4 + 1] + a.z * wv[4 * f4 + 2] +
               a.w * wv[4 * f4 + 3];
      }
      eq[m] = eqm;
      evh[(size_t)s * 576 + m * 64 + g] = __float2half(evm);  // coalesced store
    }
    int dst = __builtin_amdgcn_readfirstlane(dsts[s]);
    int src = __builtin_amdgcn_readfirstlane(srcs[s]);
    const __half* qb = qh + (size_t)dst * 1152 + g;
    const __half* kb = kh + (size_t)src * 1152 + g;
    float lacc = 0.f;
#pragma unroll
    for (int m = 0; m < 9; m++) {
      float qk = __half2float(qb[m * 64]) * __half2float(kb[m * 64]) +
                 __half2float(qb[m * 64 + 576]) * __half2float(kb[m * 64 + 576]);
      lacc += eq[m] * qk;
    }
    lacc *= 0.05892556509887896f;  // 1/sqrt(P*M*DH)=1/sqrt(288)
    lacc += __shfl_xor(lacc, 8, 64);
    lacc += __shfl_xor(lacc, 4, 64);
    lacc += __shfl_xor(lacc, 2, 64);
    lacc += __shfl_xor(lacc, 1, 64);
    if ((g & 15) == 0) {
      int h = g >> 4;
      logw[(size_t)s * 4 + h] = lacc;
      atomicMax(lmax + (size_t)dst * 4 + h, fenc(lacc));
    }
  }
}

// ---------------- K5: w = exp(logit - lmax)*cutoff (slot order), denom sum ----------
__global__ __launch_bounds__(256) void k_expw2(float* __restrict__ logw,
                                               const unsigned* __restrict__ lmax,
                                               const int* __restrict__ dsts,
                                               const float* __restrict__ cuts,
                                               float* __restrict__ denom) {
  int t = blockIdx.x * 256 + threadIdx.x;  // exact E*4
  int s = t >> 2, h = t & 3;
  int dst = dsts[s];
  float wv = expf(logw[t] - fdec(lmax[(size_t)dst * 4 + h])) * cuts[s];
  logw[t] = wv;
  unsafeAtomicAdd(denom + (size_t)dst * 4 + h, wv);
}

// ---------------- K6: CSR gather aggregation, wave per dst, coalesced fp16 ----------
__global__ __launch_bounds__(256) void k_fagg2(const __half* __restrict__ evh,
                                               const __half* __restrict__ vh,
                                               const int* __restrict__ srcs,
                                               const int* __restrict__ rowptr,
                                               const float* __restrict__ logw,
                                               const float* __restrict__ denom,
                                               float* __restrict__ attn_out) {
  int dst = (blockIdx.x * 256 + threadIdx.x) >> 6;  // exact 6000 (1500 blocks)
  int g = threadIdx.x & 63;
  int e0 = __builtin_amdgcn_readfirstlane(rowptr[dst]);
  int e1 = __builtin_amdgcn_readfirstlane(rowptr[dst + 1]);
  float invd = 1.f / (denom[(size_t)dst * 4 + (g >> 4)] + 1e-9f);
  float acc[18];
#pragma unroll
  for (int i = 0; i < 18; i++) acc[i] = 0.f;
  for (int s = e0; s < e1; s++) {
    float attn = logw[(size_t)s * 4 + (g >> 4)] * invd;
    int src = __builtin_amdgcn_readfirstlane(srcs[s]);
    const __half* eb = evh + (size_t)s * 576 + g;
    const __half* vb = vh + (size_t)src * 1152 + g;
#pragma unroll
    for (int m = 0; m < 9; m++) {
      float sc = attn * __half2float(eb[m * 64]);
      acc[m] += sc * __half2float(vb[m * 64]);
      acc[m + 9] += sc * __half2float(vb[m * 64 + 576]);
    }
  }
  float* ob = attn_out + (size_t)dst * 1152 + g;
#pragma unroll
  for (int m = 0; m < 9; m++) {
    ob[m * 64] = acc[m];
    ob[m * 64 + 576] = acc[m + 9];
  }
}

// ---------------- K7: LDS-tiled Wo projection + post-select + gate + residual -------
__global__ __launch_bounds__(256) void k_wo_post3(const float* __restrict__ attn_out,
                                                  const float* __restrict__ Wo,
                                                  const float* __restrict__ xpre,
                                                  const float* __restrict__ fnodes,
                                                  const float* __restrict__ c,
                                                  const float* __restrict__ cnt,
                                                  const float* __restrict__ cutsum,
                                                  float* __restrict__ out) {
  __shared__ __align__(16) float xt[16 * 64];  // 4 KB
  int pm = blockIdx.y;
  int p = pm / 9, dm = deg_of(pm % 9);
  int n0 = blockIdx.x * 16;
  int g = threadIdx.x & 63, w = threadIdx.x >> 6;
  for (int i = threadIdx.x; i < 1024; i += 256) {
    int r = i >> 6, f = i & 63;
    xt[i] = attn_out[((size_t)(n0 + r) * 18 + pm) * 64 + f];
  }
  const float* Wb = Wo + (size_t)(p * 3 + dm) * 4096;
  float wreg[64];
#pragma unroll
  for (int f = 0; f < 64; f++) wreg[f] = Wb[f * 64 + g];
  __syncthreads();
  for (int i = 0; i < 4; i++) {
    int r = w * 4 + i;
    int n = n0 + r;
    float acc = 0.f;
#pragma unroll
    for (int f4 = 0; f4 < 16; f4++) {
      float4 a = *(const float4*)(xt + r * 64 + f4 * 4);
      acc += a.x * wreg[4 * f4] + a.y * wreg[4 * f4 + 1] + a.z * wreg[4 * f4 + 2] +
             a.w * wreg[4 * f4 + 3];
    }
    float mc = cutsum[n] / fmaxf(cnt[n], 1.f);
    size_t idx = ((size_t)n * 18 + pm) * 64 + g;
    float post = (mc < 1e-5f) ? xpre[idx] : acc;
    float a1v = c[(size_t)n * 1664 + 448 + (p * 3 + dm) * 64 + g];
    out[idx] = fnodes[idx] + a1v * post;
  }
}

// ---------------- K9a: gelu gate from pm=0 pre-gate row; 16 nodes/block -------------
__global__ __launch_bounds__(256) void k_gate(const float* __restrict__ xp2,
                                              const float* __restrict__ W1,
                                              float* __restrict__ gatebuf) {
  __shared__ __align__(16) float xt[16 * 64];  // 4 KB
  int n0 = blockIdx.x * 16;  // 375 blocks
  int w = threadIdx.x >> 6, g = threadIdx.x & 63;
  for (int i = threadIdx.x; i < 1024; i += 256) {
    int r = i >> 6, f = i & 63;
    xt[i] = xp2[(size_t)(n0 + r) * 1152 + f];  // pm = 0 rows
  }
  float w1reg[64];
#pragma unroll
  for (int f = 0; f < 64; f++) w1reg[f] = W1[(size_t)f * 256 + w * 64 + g];
  __syncthreads();
  for (int r = 0; r < 16; r++) {
    float acc = 0.f;
#pragma unroll
    for (int f4 = 0; f4 < 16; f4++) {
      float4 a = *(const float4*)(xt + r * 64 + f4 * 4);  // LDS broadcast
      acc += a.x * w1reg[4 * f4] + a.y * w1reg[4 * f4 + 1] + a.z * w1reg[4 * f4 + 2] +
             a.w * w1reg[4 * f4 + 3];
    }
    float gt = (fabsf(acc) > 1e-4f)
                   ? 0.5f * (1.f + tanhf(0.7978845608028654f *
                                         (acc + 0.044715f * acc * acc * acc)))
                   : 0.5f;
    gatebuf[(size_t)(n0 + r) * 256 + w * 64 + g] = gt;
  }
}

// ---------------- K9b: fused MLP, parallel (n-tile, pm) grid, h never in memory -----
// out[n,pm,:] += a2 * ( gate(n,:) * (x[n,pm,:] @ W1[p,dm]) ) @ W2[p,dm]
__global__ __launch_bounds__(256) void k_mlp_par(const float* __restrict__ xp2,
                                                 const float* __restrict__ W1,
                                                 const float* __restrict__ W2,
                                                 const float* __restrict__ gatebuf,
                                                 const float* __restrict__ c,
                                                 float* __restrict__ out) {
  __shared__ __align__(16) float xt[16 * 64];   // 4 KB
  __shared__ __align__(16) float ht[16 * 256];  // 16 KB
  __shared__ float po[4][16 * 64];              // 16 KB  -> 36 KB total
  int pm = blockIdx.y;
  int p = pm / 9, dm = deg_of(pm % 9);
  int n0 = blockIdx.x * 16;  // 375 x-blocks
  int w = threadIdx.x >> 6, g = threadIdx.x & 63;
  const float* w1b = W1 + (size_t)(p * 3 + dm) * 16384;
  const float* w2b = W2 + (size_t)(p * 3 + dm) * 16384;
  float w1reg[64], w2reg[64];
#pragma unroll
  for (int f = 0; f < 64; f++) w1reg[f] = w1b[(size_t)f * 256 + w * 64 + g];
#pragma unroll
  for (int k = 0; k < 64; k++) w2reg[k] = w2b[(size_t)(w * 64 + k) * 64 + g];
  for (int i = threadIdx.x; i < 1024; i += 256) {
    int r = i >> 6, f = i & 63;
    xt[i] = xp2[((size_t)(n0 + r) * 18 + pm) * 64 + f];
  }
  __syncthreads();
  // stage1: h[r][j], j = w*64+g, gated (gate is coalesced global, L2-hot)
  for (int r = 0; r < 16; r++) {
    float acc = 0.f;
#pragma unroll
    for (int f4 = 0; f4 < 16; f4++) {
      float4 a = *(const float4*)(xt + r * 64 + f4 * 4);  // LDS broadcast
      acc += a.x * w1reg[4 * f4] + a.y * w1reg[4 * f4 + 1] + a.z * w1reg[4 * f4 + 2] +
             a.w * w1reg[4 * f4 + 3];
    }
    ht[r * 256 + w * 64 + g] = acc * gatebuf[(size_t)(n0 + r) * 256 + w * 64 + g];
  }
  __syncthreads();
  // stage2: po[w][r][g] = this wave's k-quarter partial
  for (int r = 0; r < 16; r++) {
    float acc = 0.f;
#pragma unroll
    for (int k4 = 0; k4 < 16; k4++) {
      float4 a = *(const float4*)(ht + r * 256 + w * 64 + k4 * 4);  // LDS broadcast
      acc += a.x * w2reg[4 * k4] + a.y * w2reg[4 * k4 + 1] + a.z * w2reg[4 * k4 + 2] +
             a.w * w2reg[4 * k4 + 3];
    }
    po[w][r * 64 + g] = acc;
  }
  __syncthreads();
  // reduce partials + gated residual add (coalesced RMW)
  for (int i = threadIdx.x; i < 1024; i += 256) {
    int r = i >> 6, gg = i & 63;
    float s2 = po[0][i] + po[1][i] + po[2][i] + po[3][i];
    int n = n0 + r;
    size_t idx = ((size_t)n * 18 + pm) * 64 + gg;
    out[idx] += c[(size_t)n * 1664 + 1280 + (p * 3 + dm) * 64 + gg] * s2;
  }
}

// ---------------- workspace layout (bytes) ----------------
#define OFF_C 0UL              // 39,936,000
#define OFF_XPRE 39936000UL    // 27,648,000 (reused as x_pre2)
#define OFF_QH 67584000UL      // 13,824,000 fp16 q
#define OFF_KH 81408000UL      // 13,824,000 fp16 k
#define OFF_VH 95232000UL      // 13,824,000 fp16 v
#define OFF_EVH 109056000UL    // 82,944,000 fp16 ev
#define OFF_ATTN 67584000UL    // 27,648,000 fp32 (over dead q+k after k_edge)
#define OFF_SBUF 192000000UL   // 1,536,000
#define OFF_LOGW 193536000UL   // 1,152,000
#define OFF_LMAX 194688000UL   // 96,000
#define OFF_DENOM 194784000UL  // 96,000
#define OFF_CNT 194880000UL    // 24,000
#define OFF_CUTSUM 194904000UL // 24,000
#define OFF_ROWPTR 194928000UL // 24,064
#define OFF_FILLC 194952064UL  // 24,000
#define OFF_EIDS 194976064UL   // 288,000
#define OFF_DSTS 195264064UL   // 288,000
#define OFF_SRCS 195552064UL   // 288,000
#define OFF_CUTS 195840064UL   // 288,000
#define OFF_GATE 196128064UL   // 6,144,000 (N x 256 fp32 gelu gate)
#define WS_NEEDED 202272064UL

extern "C" void kernel_launch(void* const* d_in, const int* in_sizes, int n_in,
                              void* d_out, int out_size, void* d_ws, size_t ws_size,
                              hipStream_t stream) {
  const float* f_nodes = (const float*)d_in[0];
  const float* f_edges = (const float*)d_in[1];
  const float* f_time = (const float*)d_in[2];
  const float* cutoff = (const float*)d_in[3];
  const float* ln_s = (const float*)d_in[4];
  const float* ln_b = (const float*)d_in[5];
  const float* W_c = (const float*)d_in[6];
  const float* b_c = (const float*)d_in[7];
  const float* Wq = (const float*)d_in[8];
  const float* Wk = (const float*)d_in[9];
  const float* Wv = (const float*)d_in[10];
  const float* Wo = (const float*)d_in[11];
  const float* We_qk = (const float*)d_in[12];
  const float* We_v = (const float*)d_in[13];
  const float* W1 = (const float*)d_in[14];
  const float* W2 = (const float*)d_in[15];
  const int* src_idx = (const int*)d_in[16];
  const int* dst_idx = (const int*)d_in[17];
  float* out = (float*)d_out;
  char* ws = (char*)d_ws;
  if (ws_size < WS_NEEDED) return;  // insufficient scratch; would show as poison absmax

  float* c = (float*)(ws + OFF_C);
  float* xpre = (float*)(ws + OFF_XPRE);
  __half* qh = (__half*)(ws + OFF_QH);
  __half* kh = (__half*)(ws + OFF_KH);
  __half* vh = (__half*)(ws + OFF_VH);
  __half* evh = (__half*)(ws + OFF_EVH);
  float* attn_out = (float*)(ws + OFF_ATTN);
  float* sbuf = (float*)(ws + OFF_SBUF);
  float* logw = (float*)(ws + OFF_LOGW);
  unsigned* lmax = (unsigned*)(ws + OFF_LMAX);
  float* denom = (float*)(ws + OFF_DENOM);
  float* cnt = (float*)(ws + OFF_CNT);
  float* cutsum = (float*)(ws + OFF_CUTSUM);
  int* rowptr = (int*)(ws + OFF_ROWPTR);
  int* fillc = (int*)(ws + OFF_FILLC);
  int* eids = (int*)(ws + OFF_EIDS);
  int* dsts = (int*)(ws + OFF_DSTS);
  int* srcs = (int*)(ws + OFF_SRCS);
  float* cuts = (float*)(ws + OFF_CUTS);
  float* gatebuf = (float*)(ws + OFF_GATE);

  // zero lmax/denom/cnt/cutsum (contiguous)
  hipMemsetAsync(ws + OFF_LMAX, 0, 240000, stream);

  k_ln_t<<<1500, 256, 0, stream>>>(f_time, ln_s, ln_b, sbuf);
  k_count<<<282, 256, 0, stream>>>(dst_idx, cutoff, cnt, cutsum);
  k_cond_mm<<<750, 256, 0, stream>>>(sbuf, W_c, b_c, c);
  k_scan<<<1, 1024, 0, stream>>>(cnt, rowptr, fillc);
  k_fill<<<282, 256, 0, stream>>>(dst_idx, src_idx, cutoff, fillc, eids, dsts, srcs,
                                  cuts);
  k_lnmod<<<3000, 256, 0, stream>>>(f_nodes, c, xpre, 0, 384);

  k_qkv2<<<dim3(375, 18), 192, 0, stream>>>(xpre, Wq, Wk, Wv, qh, kh, vh);

  k_edge<<<4500, 256, 0, stream>>>(f_edges, We_qk, We_v, qh, kh, eids, dsts, srcs, evh,
                                   logw, lmax);
  k_expw2<<<1125, 256, 0, stream>>>(logw, lmax, dsts, cuts, denom);
  k_fagg2<<<1500, 256, 0, stream>>>(evh, vh, srcs, rowptr, logw, denom, attn_out);
  k_wo_post3<<<dim3(375, 18), 256, 0, stream>>>(attn_out, Wo, xpre, f_nodes, c, cnt,
                                                cutsum, out);

  k_lnmod<<<3000, 256, 0, stream>>>(out, c, xpre, 832, 1216);  // x_pre2 (buffer reuse)
  k_gate<<<375, 256, 0, stream>>>(xpre, W1, gatebuf);
  k_mlp_par<<<dim3(375, 18), 256, 0, stream>>>(xpre, W1, W2, gatebuf, c, out);
}

// Round 6
// 976.250 us; speedup vs baseline: 1.3162x; 1.3162x over previous
//
#include <hip/hip_runtime.h>
#include <hip/hip_fp16.h>
#include <math.h>

// SO3 DiT layer, MI355X fp32. N=6000, E=72000, P=2, L=2, M=9, F=64, H=4, DH=16
// R3: coalesced LDS staging for edge/proj GEMMs. 1370 -> 1080 us.
// R4/R5: fused MLP (both GEMMs in one kernel) -> 128 VGPRs of weights/thread,
// 152 VGPR total, ~2 blocks/CU, latency-exposed: 545-555 us regardless of grid.
// R6: un-fuse. Two single-GEMM kernels (one 64-reg weight array each, like the
// healthy k_qkv2/k_wo_post3), h materialized in lane-coalesced [n][pm][j]
// layout (R3's mlp1/mlp2 sin was wave-uniform h indexing, not materialization;
// 220 MB of h traffic is ~35 us at HBM speed). Gate becomes elementwise.

#define NN 6000
#define EE 72000

__device__ __forceinline__ float wsum(float v) {
#pragma unroll
  for (int o = 32; o >= 1; o >>= 1) v += __shfl_xor(v, o, 64);
  return v;
}
__device__ __forceinline__ int deg_of(int m) { return (m == 0) ? 0 : ((m < 4) ? 1 : 2); }
// order-preserving float->uint for atomicMax-based segment max
__device__ __forceinline__ unsigned fenc(float x) {
  unsigned u = __float_as_uint(x);
  return (u & 0x80000000u) ? ~u : (u | 0x80000000u);
}
__device__ __forceinline__ float fdec(unsigned k) {
  unsigned u = (k & 0x80000000u) ? (k & 0x7fffffffu) : ~k;
  return __uint_as_float(u);
}

// ---------------- K1a: LayerNorm(T=64) + SiLU, one wave per node ----------------
__global__ __launch_bounds__(256) void k_ln_t(const float* __restrict__ ft,
                                              const float* __restrict__ lns,
                                              const float* __restrict__ lnb,
                                              float* __restrict__ sbuf) {
  int w = (blockIdx.x * 256 + threadIdx.x) >> 6;  // node, exact 6000
  int lane = threadIdx.x & 63;
  float t = ft[(size_t)w * 64 + lane];
  float mu = wsum(t) * (1.f / 64.f);
  float d = t - mu;
  float var = wsum(d * d) * (1.f / 64.f);
  float cin = d * rsqrtf(var + 1e-6f) * lns[lane] + lnb[lane];
  sbuf[(size_t)w * 64 + lane] = cin / (1.f + expf(-cin));
}

// ---------------- K1b: c = silu @ W_c + b_c  (64 -> 1664), 8 nodes/block ----------------
__global__ __launch_bounds__(256) void k_cond_mm(const float* __restrict__ sbuf,
                                                 const float* __restrict__ Wc,
                                                 const float* __restrict__ bc,
                                                 float* __restrict__ c) {
  __shared__ __align__(16) float st[8 * 64];  // 2 KB
  int n0 = blockIdx.x * 8;  // 750 blocks
  for (int i = threadIdx.x; i < 512; i += 256) st[i] = sbuf[(size_t)n0 * 64 + i];
  __syncthreads();
  for (int jj = threadIdx.x; jj < 1664; jj += 256) {
    float acc[8] = {0, 0, 0, 0, 0, 0, 0, 0};
#pragma unroll 8
    for (int k2 = 0; k2 < 64; k2++) {
      float wv = Wc[(size_t)k2 * 1664 + jj];
#pragma unroll
      for (int nd = 0; nd < 8; nd++) acc[nd] += st[nd * 64 + k2] * wv;
    }
    float b = bc[jj];
#pragma unroll
    for (int nd = 0; nd < 8; nd++) c[(size_t)(n0 + nd) * 1664 + jj] = acc[nd] + b;
  }
}

// ---------------- K2/K8: eqv layernorm + modulate, one wave per (n,p) ----------------
__global__ __launch_bounds__(256) void k_lnmod(const float* __restrict__ xin,
                                               const float* __restrict__ c,
                                               float* __restrict__ xout,
                                               int goff, int boff) {
  int w = (blockIdx.x * 256 + threadIdx.x) >> 6;  // (n,p) pair, exact 12000
  int lane = threadIdx.x & 63;
  int n = w >> 1, p = w & 1;
  const float* xb = xin + (size_t)w * 576 + lane;
  float x0 = xb[0], x1 = xb[64], x2 = xb[128], x3 = xb[192], x4 = xb[256];
  float x5 = xb[320], x6 = xb[384], x7 = xb[448], x8 = xb[512];
  float mu = wsum(x0) * (1.f / 64.f);
  x0 -= mu;
  float n20 = x0 * x0;
  float n21 = (x1 * x1 + x2 * x2 + x3 * x3) * (1.f / 3.f);
  float n22 = (x4 * x4 + x5 * x5 + x6 * x6 + x7 * x7 + x8 * x8) * (1.f / 5.f);
  n20 = wsum(n20) * (1.f / 64.f);
  n21 = wsum(n21) * (1.f / 64.f);
  n22 = wsum(n22) * (1.f / 64.f);
  float i0 = rsqrtf(n20 + 1e-6f), i1 = rsqrtf(n21 + 1e-6f), i2 = rsqrtf(n22 + 1e-6f);
  const float* cb = c + (size_t)n * 1664;
  float g0 = 1.f + cb[goff + p * 192 + lane];
  float g1 = 1.f + cb[goff + p * 192 + 64 + lane];
  float g2 = 1.f + cb[goff + p * 192 + 128 + lane];
  float bsh = cb[boff + lane];
  float* ob = xout + (size_t)w * 576 + lane;
  ob[0] = x0 * i0 * g0 + bsh;
  ob[64] = x1 * i1 * g1;
  ob[128] = x2 * i1 * g1;
  ob[192] = x3 * i1 * g1;
  ob[256] = x4 * i2 * g2;
  ob[320] = x5 * i2 * g2;
  ob[384] = x6 * i2 * g2;
  ob[448] = x7 * i2 * g2;
  ob[512] = x8 * i2 * g2;
}

// ---------------- CSR build: count, scan, fill ----------------
__global__ __launch_bounds__(256) void k_count(const int* __restrict__ dst_idx,
                                               const float* __restrict__ cutoff,
                                               float* __restrict__ cnt,
                                               float* __restrict__ cutsum) {
  int e = blockIdx.x * 256 + threadIdx.x;
  if (e >= EE) return;
  int d = dst_idx[e];
  unsafeAtomicAdd(cnt + d, 1.f);
  unsafeAtomicAdd(cutsum + d, cutoff[e]);
}

__global__ __launch_bounds__(1024) void k_scan(const float* __restrict__ cnt,
                                               int* __restrict__ rowptr,
                                               int* __restrict__ fillc) {
  __shared__ int part[1024];
  int t = threadIdx.x;
  int base = t * 6;  // 1024*6 = 6144 >= 6000
  int lc[6];
  int s = 0;
#pragma unroll
  for (int i = 0; i < 6; i++) {
    int idx = base + i;
    int vv = (idx < NN) ? (int)(cnt[idx] + 0.5f) : 0;
    lc[i] = s;
    s += vv;
  }
  part[t] = s;
  __syncthreads();
  for (int o = 1; o < 1024; o <<= 1) {
    int vv = (t >= o) ? part[t - o] : 0;
    __syncthreads();
    part[t] += vv;
    __syncthreads();
  }
  int ex = (t == 0) ? 0 : part[t - 1];
#pragma unroll
  for (int i = 0; i < 6; i++) {
    int idx = base + i;
    if (idx < NN) {
      int p = ex + lc[i];
      rowptr[idx] = p;
      fillc[idx] = p;
    }
  }
  if (t == 1023) rowptr[NN] = part[1023];  // == EE
}

__global__ __launch_bounds__(256) void k_fill(const int* __restrict__ dst_idx,
                                              const int* __restrict__ src_idx,
                                              const float* __restrict__ cutoff,
                                              int* __restrict__ fillc,
                                              int* __restrict__ eids,
                                              int* __restrict__ dsts,
                                              int* __restrict__ srcs,
                                              float* __restrict__ cuts) {
  int e = blockIdx.x * 256 + threadIdx.x;
  if (e >= EE) return;
  int d = dst_idx[e];
  int pos = atomicAdd(fillc + d, 1);
  eids[pos] = e;
  dsts[pos] = d;
  srcs[pos] = src_idx[e];
  cuts[pos] = cutoff[e];
}

// ---------------- K3: fused q/k/v projection, LDS-tiled, fp16 out ----------------
// grid (375, 18), 192 threads: wave = one of {q,k,v}; 16 nodes/block staged once.
__global__ __launch_bounds__(192) void k_qkv2(const float* __restrict__ xpre,
                                              const float* __restrict__ Wq,
                                              const float* __restrict__ Wk,
                                              const float* __restrict__ Wv,
                                              __half* __restrict__ qh,
                                              __half* __restrict__ kh,
                                              __half* __restrict__ vh) {
  __shared__ __align__(16) float xt[16 * 64];  // 4 KB
  int pm = blockIdx.y;
  int p = pm / 9, dm = deg_of(pm % 9);
  int n0 = blockIdx.x * 16;
  int mat = threadIdx.x >> 6;  // wave-uniform: 0=q 1=k 2=v
  int g = threadIdx.x & 63;
  for (int i = threadIdx.x; i < 1024; i += 192) {
    int r = i >> 6, f = i & 63;
    xt[i] = xpre[((size_t)(n0 + r) * 18 + pm) * 64 + f];
  }
  const float* Wsel = (mat == 0) ? Wq : ((mat == 1) ? Wk : Wv);
  const float* Wb = Wsel + (size_t)(p * 3 + dm) * 4096;
  __half* ob = (mat == 0) ? qh : ((mat == 1) ? kh : vh);
  float wreg[64];
#pragma unroll
  for (int f = 0; f < 64; f++) wreg[f] = Wb[f * 64 + g];
  __syncthreads();
  for (int r = 0; r < 16; r++) {
    float acc = 0.f;
#pragma unroll
    for (int f4 = 0; f4 < 16; f4++) {
      float4 a = *(const float4*)(xt + r * 64 + f4 * 4);  // LDS broadcast
      acc += a.x * wreg[4 * f4] + a.y * wreg[4 * f4 + 1] + a.z * wreg[4 * f4 + 2] +
             a.w * wreg[4 * f4 + 3];
    }
    ob[((size_t)(n0 + r) * 18 + pm) * 64 + g] = __float2half(acc);
  }
}

// ---------------- K4: LDS-tiled eq+ev GEMM + qk logits + segment max ----------------
// grid 4500 blocks x 256: 16 slots/block staged coalesced; wave handles 4 slots.
// eq stays in registers (never materialized); ev written fp16 once.
__global__ __launch_bounds__(256) void k_edge(const float* __restrict__ fe,
                                              const float* __restrict__ Weqk,
                                              const float* __restrict__ Wev,
                                              const __half* __restrict__ qh,
                                              const __half* __restrict__ kh,
                                              const int* __restrict__ eids,
                                              const int* __restrict__ dsts,
                                              const int* __restrict__ srcs,
                                              __half* __restrict__ evh,
                                              float* __restrict__ logw,
                                              unsigned* __restrict__ lmax) {
  __shared__ __align__(16) float ft[16 * 576];  // 36 KB
  int s0 = blockIdx.x * 16;
  int g = threadIdx.x & 63;
  int w = threadIdx.x >> 6;
  float wq[64], wv[64];
#pragma unroll
  for (int f = 0; f < 64; f++) {
    wq[f] = Weqk[f * 64 + g];
    wv[f] = Wev[f * 64 + g];
  }
  {  // coalesced stage: 16 threads per slot, 9 float4 each (256B segments)
    int sl = threadIdx.x >> 4, j = threadIdx.x & 15;
    const float* sp = fe + (size_t)eids[s0 + sl] * 576;
#pragma unroll
    for (int i = 0; i < 9; i++) {
      *(float4*)(ft + sl * 576 + i * 64 + j * 4) = *(const float4*)(sp + i * 64 + j * 4);
    }
  }
  __syncthreads();
  for (int ss = 0; ss < 4; ss++) {
    int sl = w * 4 + ss;
    int s = s0 + sl;
    float eq[9];
#pragma unroll
    for (int m = 0; m < 9; m++) {
      float eqm = 0.f, evm = 0.f;
#pragma unroll
      for (int f4 = 0; f4 < 16; f4++) {
        float4 a = *(const float4*)(ft + sl * 576 + m * 64 + f4 * 4);  // LDS broadcast
        eqm += a.x * wq[4 * f4] + a.y * wq[4 * f4 + 1] + a.z * wq[4 * f4 + 2] +
               a.w * wq[4 * f4 + 3];
        evm += a.x * wv[4 * f4] + a.y * wv[4 * f4 + 1] + a.z * wv[4 * f4 + 2] +
               a.w * wv[4 * f4 + 3];
      }
      eq[m] = eqm;
      evh[(size_t)s * 576 + m * 64 + g] = __float2half(evm);  // coalesced store
    }
    int dst = __builtin_amdgcn_readfirstlane(dsts[s]);
    int src = __builtin_amdgcn_readfirstlane(srcs[s]);
    const __half* qb = qh + (size_t)dst * 1152 + g;
    const __half* kb = kh + (size_t)src * 1152 + g;
    float lacc = 0.f;
#pragma unroll
    for (int m = 0; m < 9; m++) {
      float qk = __half2float(qb[m * 64]) * __half2float(kb[m * 64]) +
                 __half2float(qb[m * 64 + 576]) * __half2float(kb[m * 64 + 576]);
      lacc += eq[m] * qk;
    }
    lacc *= 0.05892556509887896f;  // 1/sqrt(P*M*DH)=1/sqrt(288)
    lacc += __shfl_xor(lacc, 8, 64);
    lacc += __shfl_xor(lacc, 4, 64);
    lacc += __shfl_xor(lacc, 2, 64);
    lacc += __shfl_xor(lacc, 1, 64);
    if ((g & 15) == 0) {
      int h = g >> 4;
      logw[(size_t)s * 4 + h] = lacc;
      atomicMax(lmax + (size_t)dst * 4 + h, fenc(lacc));
    }
  }
}

// ---------------- K5: w = exp(logit - lmax)*cutoff (slot order), denom sum ----------
__global__ __launch_bounds__(256) void k_expw2(float* __restrict__ logw,
                                               const unsigned* __restrict__ lmax,
                                               const int* __restrict__ dsts,
                                               const float* __restrict__ cuts,
                                               float* __restrict__ denom) {
  int t = blockIdx.x * 256 + threadIdx.x;  // exact E*4
  int s = t >> 2, h = t & 3;
  int dst = dsts[s];
  float wv = expf(logw[t] - fdec(lmax[(size_t)dst * 4 + h])) * cuts[s];
  logw[t] = wv;
  unsafeAtomicAdd(denom + (size_t)dst * 4 + h, wv);
}

// ---------------- K6: CSR gather aggregation, wave per dst, coalesced fp16 ----------
__global__ __launch_bounds__(256) void k_fagg2(const __half* __restrict__ evh,
                                               const __half* __restrict__ vh,
                                               const int* __restrict__ srcs,
                                               const int* __restrict__ rowptr,
                                               const float* __restrict__ logw,
                                               const float* __restrict__ denom,
                                               float* __restrict__ attn_out) {
  int dst = (blockIdx.x * 256 + threadIdx.x) >> 6;  // exact 6000 (1500 blocks)
  int g = threadIdx.x & 63;
  int e0 = __builtin_amdgcn_readfirstlane(rowptr[dst]);
  int e1 = __builtin_amdgcn_readfirstlane(rowptr[dst + 1]);
  float invd = 1.f / (denom[(size_t)dst * 4 + (g >> 4)] + 1e-9f);
  float acc[18];
#pragma unroll
  for (int i = 0; i < 18; i++) acc[i] = 0.f;
  for (int s = e0; s < e1; s++) {
    float attn = logw[(size_t)s * 4 + (g >> 4)] * invd;
    int src = __builtin_amdgcn_readfirstlane(srcs[s]);
    const __half* eb = evh + (size_t)s * 576 + g;
    const __half* vb = vh + (size_t)src * 1152 + g;
#pragma unroll
    for (int m = 0; m < 9; m++) {
      float sc = attn * __half2float(eb[m * 64]);
      acc[m] += sc * __half2float(vb[m * 64]);
      acc[m + 9] += sc * __half2float(vb[m * 64 + 576]);
    }
  }
  float* ob = attn_out + (size_t)dst * 1152 + g;
#pragma unroll
  for (int m = 0; m < 9; m++) {
    ob[m * 64] = acc[m];
    ob[m * 64 + 576] = acc[m + 9];
  }
}

// ---------------- K7: LDS-tiled Wo projection + post-select + gate + residual -------
__global__ __launch_bounds__(256) void k_wo_post3(const float* __restrict__ attn_out,
                                                  const float* __restrict__ Wo,
                                                  const float* __restrict__ xpre,
                                                  const float* __restrict__ fnodes,
                                                  const float* __restrict__ c,
                                                  const float* __restrict__ cnt,
                                                  const float* __restrict__ cutsum,
                                                  float* __restrict__ out) {
  __shared__ __align__(16) float xt[16 * 64];  // 4 KB
  int pm = blockIdx.y;
  int p = pm / 9, dm = deg_of(pm % 9);
  int n0 = blockIdx.x * 16;
  int g = threadIdx.x & 63, w = threadIdx.x >> 6;
  for (int i = threadIdx.x; i < 1024; i += 256) {
    int r = i >> 6, f = i & 63;
    xt[i] = attn_out[((size_t)(n0 + r) * 18 + pm) * 64 + f];
  }
  const float* Wb = Wo + (size_t)(p * 3 + dm) * 4096;
  float wreg[64];
#pragma unroll
  for (int f = 0; f < 64; f++) wreg[f] = Wb[f * 64 + g];
  __syncthreads();
  for (int i = 0; i < 4; i++) {
    int r = w * 4 + i;
    int n = n0 + r;
    float acc = 0.f;
#pragma unroll
    for (int f4 = 0; f4 < 16; f4++) {
      float4 a = *(const float4*)(xt + r * 64 + f4 * 4);
      acc += a.x * wreg[4 * f4] + a.y * wreg[4 * f4 + 1] + a.z * wreg[4 * f4 + 2] +
             a.w * wreg[4 * f4 + 3];
    }
    float mc = cutsum[n] / fmaxf(cnt[n], 1.f);
    size_t idx = ((size_t)n * 18 + pm) * 64 + g;
    float post = (mc < 1e-5f) ? xpre[idx] : acc;
    float a1v = c[(size_t)n * 1664 + 448 + (p * 3 + dm) * 64 + g];
    out[idx] = fnodes[idx] + a1v * post;
  }
}

// ---------------- K9a: h_pre[n][pm][j] = x@W1 (un-gated), (375,18) grid ------------
__global__ __launch_bounds__(256) void k_mlp1v2(const float* __restrict__ xp2,
                                                const float* __restrict__ W1,
                                                float* __restrict__ h) {
  __shared__ __align__(16) float xt[16 * 64];  // 4 KB
  int pm = blockIdx.y;
  int p = pm / 9, dm = deg_of(pm % 9);
  int n0 = blockIdx.x * 16;
  int w = threadIdx.x >> 6, g = threadIdx.x & 63;
  const float* w1b = W1 + (size_t)(p * 3 + dm) * 16384;
  float w1reg[64];
#pragma unroll
  for (int f = 0; f < 64; f++) w1reg[f] = w1b[(size_t)f * 256 + w * 64 + g];
  for (int i = threadIdx.x; i < 1024; i += 256) {
    int r = i >> 6, f = i & 63;
    xt[i] = xp2[((size_t)(n0 + r) * 18 + pm) * 64 + f];
  }
  __syncthreads();
  for (int r = 0; r < 16; r++) {
    float a0 = 0.f, a1 = 0.f, a2 = 0.f, a3 = 0.f;  // 4 chains to hide FMA latency
#pragma unroll
    for (int f4 = 0; f4 < 16; f4 += 4) {
      float4 x0 = *(const float4*)(xt + r * 64 + f4 * 4);
      float4 x1 = *(const float4*)(xt + r * 64 + f4 * 4 + 4);
      float4 x2 = *(const float4*)(xt + r * 64 + f4 * 4 + 8);
      float4 x3 = *(const float4*)(xt + r * 64 + f4 * 4 + 12);
      a0 += x0.x * w1reg[4 * f4] + x0.y * w1reg[4 * f4 + 1] + x0.z * w1reg[4 * f4 + 2] +
            x0.w * w1reg[4 * f4 + 3];
      a1 += x1.x * w1reg[4 * f4 + 4] + x1.y * w1reg[4 * f4 + 5] +
            x1.z * w1reg[4 * f4 + 6] + x1.w * w1reg[4 * f4 + 7];
      a2 += x2.x * w1reg[4 * f4 + 8] + x2.y * w1reg[4 * f4 + 9] +
            x2.z * w1reg[4 * f4 + 10] + x2.w * w1reg[4 * f4 + 11];
      a3 += x3.x * w1reg[4 * f4 + 12] + x3.y * w1reg[4 * f4 + 13] +
            x3.z * w1reg[4 * f4 + 14] + x3.w * w1reg[4 * f4 + 15];
    }
    // coalesced store: h[n][pm][j], j = w*64+g
    h[((size_t)(n0 + r) * 18 + pm) * 256 + w * 64 + g] = (a0 + a1) + (a2 + a3);
  }
}

// ---------------- K9b: gate[n][j] = gelu(s)/s from h_pre[n,pm=0,:], elementwise -----
__global__ __launch_bounds__(256) void k_gate2(const float* __restrict__ h,
                                               float* __restrict__ gatebuf) {
  int n = blockIdx.x;  // 6000 blocks
  int j = threadIdx.x;
  float s = h[(size_t)n * 4608 + j];
  float gt = (fabsf(s) > 1e-4f)
                 ? 0.5f * (1.f + tanhf(0.7978845608028654f * (s + 0.044715f * s * s * s)))
                 : 0.5f;
  gatebuf[(size_t)n * 256 + j] = gt;
}

// ---------------- K9c: out += a2 * ((h_pre*gate) @ W2), (375,18) grid ---------------
__global__ __launch_bounds__(256) void k_mlp2v2(const float* __restrict__ h,
                                                const float* __restrict__ W2,
                                                const float* __restrict__ gatebuf,
                                                const float* __restrict__ c,
                                                float* __restrict__ out) {
  __shared__ __align__(16) float ht[16 * 256];  // 16 KB
  __shared__ float po[4][16 * 64];              // 16 KB
  int pm = blockIdx.y;
  int p = pm / 9, dm = deg_of(pm % 9);
  int n0 = blockIdx.x * 16;
  int w = threadIdx.x >> 6, g = threadIdx.x & 63;
  const float* w2b = W2 + (size_t)(p * 3 + dm) * 16384;
  float w2reg[64];
#pragma unroll
  for (int k = 0; k < 64; k++) w2reg[k] = w2b[(size_t)(w * 64 + k) * 64 + g];
  for (int i = threadIdx.x; i < 4096; i += 256) {  // stage gated h tile, coalesced
    int r = i >> 8, k = i & 255;
    ht[i] = h[((size_t)(n0 + r) * 18 + pm) * 256 + k] *
            gatebuf[(size_t)(n0 + r) * 256 + k];
  }
  __syncthreads();
  for (int r = 0; r < 16; r++) {
    float a0 = 0.f, a1 = 0.f, a2 = 0.f, a3 = 0.f;
#pragma unroll
    for (int k4 = 0; k4 < 16; k4 += 4) {
      float4 h0 = *(const float4*)(ht + r * 256 + w * 64 + k4 * 4);
      float4 h1 = *(const float4*)(ht + r * 256 + w * 64 + k4 * 4 + 4);
      float4 h2 = *(const float4*)(ht + r * 256 + w * 64 + k4 * 4 + 8);
      float4 h3 = *(const float4*)(ht + r * 256 + w * 64 + k4 * 4 + 12);
      a0 += h0.x * w2reg[4 * k4] + h0.y * w2reg[4 * k4 + 1] + h0.z * w2reg[4 * k4 + 2] +
            h0.w * w2reg[4 * k4 + 3];
      a1 += h1.x * w2reg[4 * k4 + 4] + h1.y * w2reg[4 * k4 + 5] +
            h1.z * w2reg[4 * k4 + 6] + h1.w * w2reg[4 * k4 + 7];
      a2 += h2.x * w2reg[4 * k4 + 8] + h2.y * w2reg[4 * k4 + 9] +
            h2.z * w2reg[4 * k4 + 10] + h2.w * w2reg[4 * k4 + 11];
      a3 += h3.x * w2reg[4 * k4 + 12] + h3.y * w2reg[4 * k4 + 13] +
            h3.z * w2reg[4 * k4 + 14] + h3.w * w2reg[4 * k4 + 15];
    }
    po[w][r * 64 + g] = (a0 + a1) + (a2 + a3);
  }
  __syncthreads();
  for (int i = threadIdx.x; i < 1024; i += 256) {
    int r = i >> 6, gg = i & 63;
    float s2 = po[0][i] + po[1][i] + po[2][i] + po[3][i];
    int n = n0 + r;
    size_t idx = ((size_t)n * 18 + pm) * 64 + gg;
    out[idx] += c[(size_t)n * 1664 + 1280 + (p * 3 + dm) * 64 + gg] * s2;
  }
}

// ---------------- workspace layout (bytes) ----------------
#define OFF_C 0UL              // 39,936,000
#define OFF_XPRE 39936000UL    // 27,648,000 (reused as x_pre2)
#define OFF_QH 67584000UL      // 13,824,000 fp16 q
#define OFF_KH 81408000UL      // 13,824,000 fp16 k
#define OFF_VH 95232000UL      // 13,824,000 fp16 v
#define OFF_EVH 109056000UL    // 82,944,000 fp16 ev
#define OFF_ATTN 67584000UL    // 27,648,000 fp32 (over dead q+k after k_edge)
#define OFF_H 67584000UL       // 110,592,000 h_pre (over q,k,v,attn,ev — dead by MLP)
#define OFF_SBUF 192000000UL   // 1,536,000
#define OFF_LOGW 193536000UL   // 1,152,000
#define OFF_LMAX 194688000UL   // 96,000
#define OFF_DENOM 194784000UL  // 96,000
#define OFF_CNT 194880000UL    // 24,000
#define OFF_CUTSUM 194904000UL // 24,000
#define OFF_ROWPTR 194928000UL // 24,064
#define OFF_FILLC 194952064UL  // 24,000
#define OFF_EIDS 194976064UL   // 288,000
#define OFF_DSTS 195264064UL   // 288,000
#define OFF_SRCS 195552064UL   // 288,000
#define OFF_CUTS 195840064UL   // 288,000
#define OFF_GATE 196128064UL   // 6,144,000 (N x 256 fp32 gelu gate)
#define WS_NEEDED 202272064UL

extern "C" void kernel_launch(void* const* d_in, const int* in_sizes, int n_in,
                              void* d_out, int out_size, void* d_ws, size_t ws_size,
                              hipStream_t stream) {
  const float* f_nodes = (const float*)d_in[0];
  const float* f_edges = (const float*)d_in[1];
  const float* f_time = (const float*)d_in[2];
  const float* cutoff = (const float*)d_in[3];
  const float* ln_s = (const float*)d_in[4];
  const float* ln_b = (const float*)d_in[5];
  const float* W_c = (const float*)d_in[6];
  const float* b_c = (const float*)d_in[7];
  const float* Wq = (const float*)d_in[8];
  const float* Wk = (const float*)d_in[9];
  const float* Wv = (const float*)d_in[10];
  const float* Wo = (const float*)d_in[11];
  const float* We_qk = (const float*)d_in[12];
  const float* We_v = (const float*)d_in[13];
  const float* W1 = (const float*)d_in[14];
  const float* W2 = (const float*)d_in[15];
  const int* src_idx = (const int*)d_in[16];
  const int* dst_idx = (const int*)d_in[17];
  float* out = (float*)d_out;
  char* ws = (char*)d_ws;
  if (ws_size < WS_NEEDED) return;  // insufficient scratch; would show as poison absmax

  float* c = (float*)(ws + OFF_C);
  float* xpre = (float*)(ws + OFF_XPRE);
  __half* qh = (__half*)(ws + OFF_QH);
  __half* kh = (__half*)(ws + OFF_KH);
  __half* vh = (__half*)(ws + OFF_VH);
  __half* evh = (__half*)(ws + OFF_EVH);
  float* attn_out = (float*)(ws + OFF_ATTN);
  float* hbuf = (float*)(ws + OFF_H);
  float* sbuf = (float*)(ws + OFF_SBUF);
  float* logw = (float*)(ws + OFF_LOGW);
  unsigned* lmax = (unsigned*)(ws + OFF_LMAX);
  float* denom = (float*)(ws + OFF_DENOM);
  float* cnt = (float*)(ws + OFF_CNT);
  float* cutsum = (float*)(ws + OFF_CUTSUM);
  int* rowptr = (int*)(ws + OFF_ROWPTR);
  int* fillc = (int*)(ws + OFF_FILLC);
  int* eids = (int*)(ws + OFF_EIDS);
  int* dsts = (int*)(ws + OFF_DSTS);
  int* srcs = (int*)(ws + OFF_SRCS);
  float* cuts = (float*)(ws + OFF_CUTS);
  float* gatebuf = (float*)(ws + OFF_GATE);

  // zero lmax/denom/cnt/cutsum (contiguous)
  hipMemsetAsync(ws + OFF_LMAX, 0, 240000, stream);

  k_ln_t<<<1500, 256, 0, stream>>>(f_time, ln_s, ln_b, sbuf);
  k_count<<<282, 256, 0, stream>>>(dst_idx, cutoff, cnt, cutsum);
  k_cond_mm<<<750, 256, 0, stream>>>(sbuf, W_c, b_c, c);
  k_scan<<<1, 1024, 0, stream>>>(cnt, rowptr, fillc);
  k_fill<<<282, 256, 0, stream>>>(dst_idx, src_idx, cutoff, fillc, eids, dsts, srcs,
                                  cuts);
  k_lnmod<<<3000, 256, 0, stream>>>(f_nodes, c, xpre, 0, 384);

  k_qkv2<<<dim3(375, 18), 192, 0, stream>>>(xpre, Wq, Wk, Wv, qh, kh, vh);

  k_edge<<<4500, 256, 0, stream>>>(f_edges, We_qk, We_v, qh, kh, eids, dsts, srcs, evh,
                                   logw, lmax);
  k_expw2<<<1125, 256, 0, stream>>>(logw, lmax, dsts, cuts, denom);
  k_fagg2<<<1500, 256, 0, stream>>>(evh, vh, srcs, rowptr, logw, denom, attn_out);
  k_wo_post3<<<dim3(375, 18), 256, 0, stream>>>(attn_out, Wo, xpre, f_nodes, c, cnt,
                                                cutsum, out);

  k_lnmod<<<3000, 256, 0, stream>>>(out, c, xpre, 832, 1216);  // x_pre2 (buffer reuse)
  k_mlp1v2<<<dim3(375, 18), 256, 0, stream>>>(xpre, W1, hbuf);
  k_gate2<<<6000, 256, 0, stream>>>(hbuf, gatebuf);
  k_mlp2v2<<<dim3(375, 18), 256, 0, stream>>>(hbuf, W2, gatebuf, c, out);
}